// Round 8
// baseline (897.050 us; speedup 1.0000x reference)
//
#include <hip/hip_runtime.h>
#include <hip/hip_bf16.h>

typedef unsigned short u16;
typedef __bf16 bf16x8 __attribute__((ext_vector_type(8)));   // MFMA A/B operand (4 VGPRs)
typedef float  f32x4  __attribute__((ext_vector_type(4)));   // MFMA C/D operand
typedef u16    u16x8  __attribute__((ext_vector_type(8)));

#define HID   96
#define LDP   104          // padded LDS row stride for activation slices
#define MROWS 93312        // B*N*D
#define BN    10368        // B*N
#define GRID_TILE 1458     // MROWS/64

// B-fragment-ordered weights: 20 chunks x 18 frags x 512 elems (1KB frags)
// chunk: 0-2 crW, 3-5 drW, 6 W1b, 7 W1c, 8-9 gmW2, 10-11 rW12,
//        12-15 Wih (gate n-ranges i,f,g,o), 16-19 Whh
#define FCH 9216           // elems per chunk (18*512)

#define MFMA(a,b,c) __builtin_amdgcn_mfma_f32_16x16x32_bf16((a),(b),(c),0,0,0)

__device__ __forceinline__ float bf2f(u16 x){
  union { float f; unsigned u; } v; v.u = ((unsigned)x) << 16; return v.f;
}
__device__ __forceinline__ u16 f2bf(float f){
  union { float f; unsigned u; } v; v.f = f;
  unsigned r = v.u + 0x7fffu + ((v.u >> 16) & 1u);   // RNE
  return (u16)(r >> 16);
}
__device__ __forceinline__ float sigf(float x){ return 1.f/(1.f + __expf(-x)); }
__device__ __forceinline__ float tanhf_(float x){
  float xx = fminf(fmaxf(x, -15.f), 15.f);
  float e = __expf(-2.f * xx);
  return (1.f - e) / (1.f + e);
}
// in-wave LDS write->read ordering (no cross-wave data: barrier-free kernels)
__device__ __forceinline__ void lds_fence(){
  asm volatile("s_waitcnt lgkmcnt(0)" ::: "memory");
}

// ---- fragment loaders -------------------------------------------------------
struct Frags { bf16x8 a0, a1, a2; };

__device__ __forceinline__ Frags load_afrags_g(const u16* __restrict__ A, size_t row0, int lane){
  int t16 = lane & 15, q = lane >> 4;
  const u16* p = A + (row0 + (size_t)t16) * 96 + q * 8;
  Frags f;
  f.a0 = *reinterpret_cast<const bf16x8*>(p);
  f.a1 = *reinterpret_cast<const bf16x8*>(p + 32);
  f.a2 = *reinterpret_cast<const bf16x8*>(p + 64);
  return f;
}
__device__ __forceinline__ Frags load_afrags_s(const u16* sA, int row0, int lane){
  int t16 = lane & 15, q = lane >> 4;
  const u16* p = sA + (row0 + t16) * LDP + q * 8;
  Frags f;
  f.a0 = *reinterpret_cast<const bf16x8*>(p);
  f.a1 = *reinterpret_cast<const bf16x8*>(p + 32);
  f.a2 = *reinterpret_cast<const bf16x8*>(p + 64);
  return f;
}

// ---- one 16x96 layer, weights as global B-frags (L1/L2-resident) ------------
__device__ __forceinline__ void layer_g(Frags f, const u16* __restrict__ wb,
    const float* __restrict__ bias, u16* dst, int dstStride, size_t rowBase,
    bool relu, int lane)
{
  int t16 = lane & 15, q = lane >> 4;
  #pragma unroll
  for (int nt = 0; nt < 6; nt++){
    float b = bias ? bias[nt * 16 + t16] : 0.f;
    f32x4 acc = {b, b, b, b};
    const u16* wp = wb + nt * 1536 + lane * 8;
    acc = MFMA(f.a0, *reinterpret_cast<const bf16x8*>(wp),        acc);
    acc = MFMA(f.a1, *reinterpret_cast<const bf16x8*>(wp + 512),  acc);
    acc = MFMA(f.a2, *reinterpret_cast<const bf16x8*>(wp + 1024), acc);
    #pragma unroll
    for (int j = 0; j < 4; j++){
      float v = acc[j];
      if (relu) v = fmaxf(v, 0.f);
      dst[(rowBase + q * 4 + j) * (size_t)dstStride + nt * 16 + t16] = f2bf(v);
    }
  }
}

// 6 col-tiles accumulated into acc[tbase..tbase+6), weights from global frags
__device__ __forceinline__ void mfma6_g(f32x4* acc, int tbase, Frags f,
    const u16* __restrict__ wb, int lane)
{
  #pragma unroll
  for (int jt = 0; jt < 6; jt++){
    const u16* wp = wb + jt * 1536 + lane * 8;
    acc[tbase + jt] = MFMA(f.a0, *reinterpret_cast<const bf16x8*>(wp),        acc[tbase + jt]);
    acc[tbase + jt] = MFMA(f.a1, *reinterpret_cast<const bf16x8*>(wp + 512),  acc[tbase + jt]);
    acc[tbase + jt] = MFMA(f.a2, *reinterpret_cast<const bf16x8*>(wp + 1024), acc[tbase + jt]);
  }
}

// ============================================================================
// K_prep2: f32 weights -> bf16 B-fragment layout.
// frag elem (f, l, j): nt=f/3, kc=f%3, n=nt*16+(l&15), k=(l>>4)*8+kc*32+j
__global__ __launch_bounds__(256) void k_prep2(const float* __restrict__ crW,
    const float* __restrict__ drW, const float* __restrict__ gmW1,
    const float* __restrict__ gmW2, const float* __restrict__ rW12,
    const float* __restrict__ Wih, const float* __restrict__ Whh,
    u16* __restrict__ pWB)
{
  int b = blockIdx.x, tid = threadIdx.x;
  u16* dst = pWB + b * FCH;
  if (b < 12){
    const float* src;                           // row-major [k][n]
    if (b < 3)       src = crW  + b * 9216;
    else if (b < 6)  src = drW  + (b - 3) * 9216;
    else if (b == 6) src = gmW1 + 9216;
    else if (b == 7) src = gmW1 + 18432;
    else if (b < 10) src = gmW2 + (b - 8) * 9216;
    else             src = rW12 + (b - 10) * 9216;
    #pragma unroll
    for (int i = 0; i < 36; i++){
      int idx = tid + i * 256;
      int f = idx >> 9, rem = idx & 511, l = rem >> 3, j = rem & 7;
      int nt = f / 3, kc = f - nt * 3;
      int n = nt * 16 + (l & 15);
      int k = ((l >> 4) << 3) + kc * 32 + j;
      dst[idx] = f2bf(src[k * 96 + n]);
    }
  } else {
    int bb = b - 12;                            // 0..3 Wih chunks, 4..7 Whh
    const float* src = (bb < 4 ? Wih : Whh) + (bb & 3) * 9216;  // [n][k]
    #pragma unroll
    for (int i = 0; i < 36; i++){
      int idx = tid + i * 256;
      int f = idx >> 9, rem = idx & 511, l = rem >> 3, j = rem & 7;
      int nt = f / 3, kc = f - nt * 3;
      int n = nt * 16 + (l & 15);
      int k = ((l >> 4) << 3) + kc * 32 + j;
      dst[idx] = f2bf(src[n * 96 + k]);
    }
  }
}

// K0: tables (f32)
__global__ void k_tables(const float* __restrict__ eW1, const float* __restrict__ eb1,
                         const float* __restrict__ eW2, const float* __restrict__ eb2,
                         const float* __restrict__ gmW1, const float* __restrict__ gmb1,
                         float* __restrict__ XTab, float* __restrict__ XgTab)
{
  __shared__ float sX[3][96];
  int j = threadIdx.x;
  if (j < 96){
    for (int ch = 0; ch < 3; ch++){
      float acc = eb2[j];
      for (int e = 0; e < 16; e++){
        float hv = fmaxf(eW1[ch * 16 + e] + eb1[e], 0.f);
        acc += hv * eW2[e * 96 + j];
      }
      sX[ch][j] = acc;
      XTab[ch * 96 + j] = acc;
    }
  }
  __syncthreads();
  if (j < 96){
    for (int ch = 0; ch < 3; ch++){
      float acc = gmb1[j];
      for (int k = 0; k < 96; k++) acc += sX[ch][k] * gmW1[k * 96 + j];
      XgTab[ch * 96 + j] = acc;
    }
  }
}

// K_init: h only (c0 read directly on iter 0)
__global__ __launch_bounds__(256) void k_init(const int* __restrict__ inputs,
    const float* __restrict__ XTab, u16* __restrict__ h)
{
  int idx = blockIdx.x * 256 + threadIdx.x;     // exactly MROWS*12
  int m = idx / 12, h8 = idx - m * 12;
  int bn = m / 9, d = m - bn * 9;
  int inp = inputs[bn];
  int ch = (inp == 0) ? 0 : ((inp == d + 1) ? 1 : 2);
  const float* xt = XTab + ch * 96 + h8 * 8;
  u16* hp = h + (size_t)m * 96 + h8 * 8;
  #pragma unroll
  for (int e = 0; e < 8; e++) hp[e] = f2bf(xt[e]);
}

// K_AB3: h -> cr3 -> @W1b = Y;  h -> dr3 -> @W1c = Z. Barrier-free.
__global__ __launch_bounds__(256) void k_ab3(const u16* __restrict__ h,
    u16* __restrict__ Y, u16* __restrict__ Z,
    const u16* __restrict__ pWB, const float* __restrict__ crB,
    const float* __restrict__ drB)
{
  __shared__ u16 sA[64 * LDP];                  // wave-private 16-row slices
  const int tid = threadIdx.x, lane = tid & 63, wave = tid >> 6;
  const int wrow = wave * 16;
  const size_t rbase = (size_t)blockIdx.x * 64;

  Frags hf = load_afrags_g(h, rbase + wrow, lane);

  layer_g(hf, pWB, crB, sA, LDP, wrow, true, lane);                  lds_fence();
  Frags f = load_afrags_s(sA, wrow, lane);
  layer_g(f, pWB + 1 * FCH, crB + 96, sA, LDP, wrow, true, lane);    lds_fence();
  f = load_afrags_s(sA, wrow, lane);
  layer_g(f, pWB + 2 * FCH, crB + 192, sA, LDP, wrow, false, lane);  lds_fence();
  f = load_afrags_s(sA, wrow, lane);
  layer_g(f, pWB + 6 * FCH, nullptr, Y, 96, rbase + wrow, false, lane);
  lds_fence();

  layer_g(hf, pWB + 3 * FCH, drB, sA, LDP, wrow, true, lane);        lds_fence();
  f = load_afrags_s(sA, wrow, lane);
  layer_g(f, pWB + 4 * FCH, drB + 96, sA, LDP, wrow, true, lane);    lds_fence();
  f = load_afrags_s(sA, wrow, lane);
  layer_g(f, pWB + 5 * FCH, drB + 192, sA, LDP, wrow, false, lane);  lds_fence();
  f = load_afrags_s(sA, wrow, lane);
  layer_g(f, pWB + 7 * FCH, nullptr, Z, 96, rbase + wrow, false, lane);
}

// K_scell: Ssum[bn,:] = sum_d Y[bn,d,:]
__global__ __launch_bounds__(256) void k_scell(const u16* __restrict__ Y,
    u16* __restrict__ Ssum)
{
  int idx = blockIdx.x * 256 + threadIdx.x;     // exactly BN*12
  int bn = idx / 12, h8 = idx - bn * 12;
  const u16* base = Y + (size_t)bn * 864 + h8 * 8;
  float s[8];
  #pragma unroll
  for (int e = 0; e < 8; e++) s[e] = 0.f;
  #pragma unroll
  for (int d = 0; d < 9; d++){
    u16x8 v = *reinterpret_cast<const u16x8*>(base + d * 96);
    #pragma unroll
    for (int e = 0; e < 8; e++) s[e] += bf2f(v[e]);
  }
  u16x8 o;
  #pragma unroll
  for (int e = 0; e < 8; e++) o[e] = f2bf(s[e]);
  *reinterpret_cast<u16x8*>(Ssum + (size_t)bn * 96 + h8 * 8) = o;
}

__device__ __forceinline__ void addrow(float* s, const u16* p){
  u16x8 t = *reinterpret_cast<const u16x8*>(p);
  #pragma unroll
  for (int e = 0; e < 8; e++) s[e] += bf2f(t[e]);
}

// K4: msg_digit in-place per (b,d) slice
__global__ __launch_bounds__(256) void k_msgdigit(u16* __restrict__ buf)
{
  __shared__ u16 sT[81 * LDP];
  const int tid = threadIdx.x;
  const int b = blockIdx.x / 9, d = blockIdx.x - b * 9;
  const size_t base = ((size_t)b * 729 + d) * 96;
  for (int i = tid; i < 972; i += 256){
    int n = i / 12, k8 = i - n * 12;
    *reinterpret_cast<u16x8*>(sT + n * LDP + k8 * 8) =
      *reinterpret_cast<const u16x8*>(buf + base + (size_t)n * 864 + k8 * 8);
  }
  __syncthreads();
  for (int i = tid; i < 972; i += 256){
    int m = i / 12, k8 = i - m * 12;
    int r = m / 9, cc = m - r * 9;
    int br = (r / 3) * 3, bc = (cc / 3) * 3;
    float s[8];
    #pragma unroll
    for (int e = 0; e < 8; e++) s[e] = 0.f;
    #pragma unroll
    for (int c2 = 0; c2 < 9; c2++) if (c2 != cc) addrow(s, sT + (r * 9 + c2) * LDP + k8 * 8);
    #pragma unroll
    for (int r2 = 0; r2 < 9; r2++) if (r2 != r) addrow(s, sT + (r2 * 9 + cc) * LDP + k8 * 8);
    #pragma unroll
    for (int r2 = 0; r2 < 3; r2++)
      #pragma unroll
      for (int c2 = 0; c2 < 3; c2++){
        int rr = br + r2, c3 = bc + c2;
        if (rr != r && c3 != cc) addrow(s, sT + (rr * 9 + c3) * LDP + k8 * 8);
      }
    u16x8 o;
    #pragma unroll
    for (int e = 0; e < 8; e++) o[e] = f2bf(s[e]);
    *reinterpret_cast<u16x8*>(buf + base + (size_t)m * 864 + k8 * 8) = o;
  }
}

// K_GLR4: g1 + gm W2 + LSTM (two 12-tile gate passes) + readout. Barrier-free.
// Gate split halves accumulator footprint: pass1 i,g -> partial=sig(i)*tanh(g)
// in 24 VGPRs; pass2 f,o with cold prefetched. Peak regs ~150 vs ~196 (acc[24]).
__global__ __launch_bounds__(256) void k_glr4(const u16* __restrict__ Y,
    const u16* __restrict__ Zd, const u16* __restrict__ Ssum,
    const int* __restrict__ inputs, const float* __restrict__ XgTab,
    const u16* __restrict__ pWB, const float* __restrict__ gmb2,
    u16* __restrict__ h, const float* __restrict__ cin, float* __restrict__ cout,
    const float* __restrict__ bih, const float* __restrict__ bhh,
    const float* __restrict__ rb12, const float* __restrict__ rW3,
    const float* __restrict__ rb3, float* __restrict__ out)
{
  __shared__ u16 sA[64 * LDP];                  // wave-private 16-row slices
  const int tid = threadIdx.x, lane = tid & 63, wave = tid >> 6;
  const int t16 = lane & 15, q = lane >> 4;
  const int wrow = wave * 16;
  const size_t rbase = (size_t)blockIdx.x * 64;

  Frags ah = load_afrags_g(h, rbase + wrow, lane);

  // g1 = relu(Xg[ch] + (Ssum - Y) + Zd) -> own sA rows
  for (int i = lane; i < 192; i += 64){
    int rl = i / 12, kc = i - rl * 12;
    int m = (int)rbase + wrow + rl;
    int bn = m / 9, d = m - bn * 9;
    int inp = inputs[bn];
    int ch = (inp == 0) ? 0 : ((inp == d + 1) ? 1 : 2);
    const float* xg = XgTab + ch * 96 + kc * 8;
    u16x8 vy = *reinterpret_cast<const u16x8*>(Y    + (size_t)m * 96 + kc * 8);
    u16x8 vz = *reinterpret_cast<const u16x8*>(Zd   + (size_t)m * 96 + kc * 8);
    u16x8 vs = *reinterpret_cast<const u16x8*>(Ssum + (size_t)bn * 96 + kc * 8);
    u16x8 o;
    #pragma unroll
    for (int e = 0; e < 8; e++)
      o[e] = f2bf(fmaxf(xg[e] + bf2f(vs[e]) - bf2f(vy[e]) + bf2f(vz[e]), 0.f));
    *reinterpret_cast<u16x8*>(sA + (wrow + rl) * LDP + kc * 8) = o;
  }
  lds_fence();

  Frags f = load_afrags_s(sA, wrow, lane);
  layer_g(f, pWB + 8 * FCH, gmb2, sA, LDP, wrow, true, lane);        lds_fence();
  f = load_afrags_s(sA, wrow, lane);
  layer_g(f, pWB + 9 * FCH, gmb2 + 96, sA, LDP, wrow, false, lane);  lds_fence();
  Frags ax = load_afrags_s(sA, wrow, lane);

  // ---- LSTM pass 1: gates i (n 0..95) and g (n 192..287) ----
  f32x4 acc[12];
  #pragma unroll
  for (int jt = 0; jt < 6; jt++){
    int n = jt * 16 + t16;
    float b0 = bih[n] + bhh[n];
    float b1 = bih[n + 192] + bhh[n + 192];
    f32x4 a0 = {b0, b0, b0, b0};
    f32x4 a1 = {b1, b1, b1, b1};
    acc[jt] = a0; acc[6 + jt] = a1;
  }
  mfma6_g(acc, 0, ax, pWB + 12 * FCH, lane);   // Wih i
  mfma6_g(acc, 0, ah, pWB + 16 * FCH, lane);   // Whh i
  mfma6_g(acc, 6, ax, pWB + 14 * FCH, lane);   // Wih g
  mfma6_g(acc, 6, ah, pWB + 18 * FCH, lane);   // Whh g

  float partial[6][4];
  #pragma unroll
  for (int jt = 0; jt < 6; jt++)
    #pragma unroll
    for (int j = 0; j < 4; j++)
      partial[jt][j] = sigf(acc[jt][j]) * tanhf_(acc[6 + jt][j]);

  // prefetch cold (latency hides under pass-2 MFMAs)
  float cold[6][4];
  #pragma unroll
  for (int jt = 0; jt < 6; jt++)
    #pragma unroll
    for (int j = 0; j < 4; j++)
      cold[jt][j] = cin[(rbase + wrow + q * 4 + j) * 96 + jt * 16 + t16];

  // ---- LSTM pass 2: gates f (n 96..191) and o (n 288..383) ----
  #pragma unroll
  for (int jt = 0; jt < 6; jt++){
    int n = jt * 16 + t16;
    float b0 = bih[n + 96] + bhh[n + 96];
    float b1 = bih[n + 288] + bhh[n + 288];
    f32x4 a0 = {b0, b0, b0, b0};
    f32x4 a1 = {b1, b1, b1, b1};
    acc[jt] = a0; acc[6 + jt] = a1;
  }
  mfma6_g(acc, 0, ax, pWB + 13 * FCH, lane);   // Wih f
  mfma6_g(acc, 0, ah, pWB + 17 * FCH, lane);   // Whh f
  mfma6_g(acc, 6, ax, pWB + 15 * FCH, lane);   // Wih o
  mfma6_g(acc, 6, ah, pWB + 19 * FCH, lane);   // Whh o

  // Epilogue: c/h update; h_new -> global + own sA rows
  #pragma unroll
  for (int jt = 0; jt < 6; jt++)
    #pragma unroll
    for (int j = 0; j < 4; j++){
      size_t m = rbase + wrow + q * 4 + j;
      int col = jt * 16 + t16;
      float cn = sigf(acc[jt][j]) * cold[jt][j] + partial[jt][j];
      float hn = sigf(acc[6 + jt][j]) * tanhf_(cn);
      cout[m * 96 + col] = cn;
      u16 hb = f2bf(hn);
      h[m * 96 + col] = hb;
      sA[(wrow + q * 4 + j) * LDP + col] = hb;
    }
  lds_fence();

  // Readout
  f = load_afrags_s(sA, wrow, lane);
  layer_g(f, pWB + 10 * FCH, rb12, sA, LDP, wrow, true, lane);       lds_fence();
  f = load_afrags_s(sA, wrow, lane);
  layer_g(f, pWB + 11 * FCH, rb12 + 96, sA, LDP, wrow, true, lane);  lds_fence();

  // Final dot over own rows: out[row] = sA[row,:] . rW3 + rb3
  int row = tid >> 2, part = tid & 3;
  float s = 0.f;
  const u16* rp = sA + row * LDP + part * 24;
  #pragma unroll
  for (int k = 0; k < 24; k++) s += bf2f(rp[k]) * rW3[part * 24 + k];
  s += __shfl_xor(s, 1);
  s += __shfl_xor(s, 2);
  if (part == 0) out[rbase + row] = s + rb3[0];
}

// ============================================================================
extern "C" void kernel_launch(void* const* d_in, const int* in_sizes, int n_in,
                              void* d_out, int out_size, void* d_ws, size_t ws_size,
                              hipStream_t stream)
{
  (void)in_sizes; (void)n_in; (void)out_size; (void)ws_size;
  const int*   inputs = (const int*)d_in[0];
  const float* c0     = (const float*)d_in[1];
  const float* eW1  = (const float*)d_in[4];
  const float* eb1  = (const float*)d_in[5];
  const float* eW2  = (const float*)d_in[6];
  const float* eb2  = (const float*)d_in[7];
  const float* crW  = (const float*)d_in[8];
  const float* crB  = (const float*)d_in[9];
  const float* drW  = (const float*)d_in[10];
  const float* drB  = (const float*)d_in[11];
  const float* gmW1 = (const float*)d_in[12];
  const float* gmb1 = (const float*)d_in[13];
  const float* gmW2 = (const float*)d_in[14];
  const float* gmb2 = (const float*)d_in[15];
  const float* Wih  = (const float*)d_in[16];
  const float* Whh  = (const float*)d_in[17];
  const float* bih  = (const float*)d_in[18];
  const float* bhh  = (const float*)d_in[19];
  const float* rW12 = (const float*)d_in[20];
  const float* rb12 = (const float*)d_in[21];
  const float* rW3  = (const float*)d_in[22];
  const float* rb3  = (const float*)d_in[23];

  char* ws = (char*)d_ws;
  float* XgTab = (float*)(ws);
  float* XTab  = (float*)(ws + 4096);
  u16*   pWB   = (u16*)(ws + 8192);              // 20*9216*2 = 368640 B
  u16* h  = (u16*)(ws + 8192 + 401408);
  u16* B1 = h  + (size_t)MROWS * 96;             // Y
  u16* B2 = B1 + (size_t)MROWS * 96;             // Z / Zd
  float* c = (float*)(B2 + (size_t)MROWS * 96);
  u16* Ssum = (u16*)(c + (size_t)MROWS * 96);    // BN*96 bf16
  float* out = (float*)d_out;

  k_prep2<<<20, 256, 0, stream>>>(crW, drW, gmW1, gmW2, rW12, Wih, Whh, pWB);
  k_tables<<<1, 128, 0, stream>>>(eW1, eb1, eW2, eb2, gmW1, gmb1, XTab, XgTab);
  k_init<<<(MROWS * 12) / 256, 256, 0, stream>>>(inputs, XTab, h);

  for (int it = 0; it < 4; ++it){
    const float* cin = (it == 0) ? c0 : c;
    k_ab3<<<GRID_TILE, 256, 0, stream>>>(h, B1, B2, pWB, crB, drB);
    k_scell<<<(BN * 12) / 256, 256, 0, stream>>>(B1, Ssum);
    k_msgdigit<<<128 * 9, 256, 0, stream>>>(B2);
    k_glr4<<<GRID_TILE, 256, 0, stream>>>(B1, B2, Ssum, inputs, XgTab, pWB, gmb2,
                                          h, cin, c, bih, bhh, rb12, rW3, rb3,
                                          out + (size_t)it * MROWS);
  }
}

// Round 9
// 888.240 us; speedup vs baseline: 1.0099x; 1.0099x over previous
//
#include <hip/hip_runtime.h>
#include <hip/hip_bf16.h>

typedef unsigned short u16;
typedef __bf16 bf16x8 __attribute__((ext_vector_type(8)));   // MFMA A/B operand (4 VGPRs)
typedef float  f32x4  __attribute__((ext_vector_type(4)));   // MFMA C/D operand
typedef u16    u16x8  __attribute__((ext_vector_type(8)));

#define HID   96
#define LDP   104          // padded LDS row stride for activation slices
#define MROWS 93312        // B*N*D
#define BN    10368        // B*N
#define GRID_TILE 1458     // MROWS/64

// B-fragment-ordered weights: 20 chunks x 18 frags x 512 elems (1KB frags)
// chunk: 0-2 crW, 3-5 drW, 6 W1b, 7 W1c, 8-9 gmW2, 10-11 rW12,
//        12-15 Wih (gate n-ranges i,f,g,o), 16-19 Whh
#define FCH 9216           // elems per chunk (18*512)

#define MFMA(a,b,c) __builtin_amdgcn_mfma_f32_16x16x32_bf16((a),(b),(c),0,0,0)

__device__ __forceinline__ float bf2f(u16 x){
  union { float f; unsigned u; } v; v.u = ((unsigned)x) << 16; return v.f;
}
__device__ __forceinline__ u16 f2bf(float f){
  union { float f; unsigned u; } v; v.f = f;
  unsigned r = v.u + 0x7fffu + ((v.u >> 16) & 1u);   // RNE
  return (u16)(r >> 16);
}
__device__ __forceinline__ float sigf(float x){ return 1.f/(1.f + __expf(-x)); }
__device__ __forceinline__ float tanhf_(float x){
  float xx = fminf(fmaxf(x, -15.f), 15.f);
  float e = __expf(-2.f * xx);
  return (1.f - e) / (1.f + e);
}
// in-wave LDS write->read ordering (no cross-wave data: barrier-free kernels)
__device__ __forceinline__ void lds_fence(){
  asm volatile("s_waitcnt lgkmcnt(0)" ::: "memory");
}

// ---- fragment loaders -------------------------------------------------------
struct Frags { bf16x8 a0, a1, a2; };

__device__ __forceinline__ Frags load_afrags_g(const u16* __restrict__ A, size_t row0, int lane){
  int t16 = lane & 15, q = lane >> 4;
  const u16* p = A + (row0 + (size_t)t16) * 96 + q * 8;
  Frags f;
  f.a0 = *reinterpret_cast<const bf16x8*>(p);
  f.a1 = *reinterpret_cast<const bf16x8*>(p + 32);
  f.a2 = *reinterpret_cast<const bf16x8*>(p + 64);
  return f;
}
__device__ __forceinline__ Frags load_afrags_s(const u16* sA, int row0, int lane){
  int t16 = lane & 15, q = lane >> 4;
  const u16* p = sA + (row0 + t16) * LDP + q * 8;
  Frags f;
  f.a0 = *reinterpret_cast<const bf16x8*>(p);
  f.a1 = *reinterpret_cast<const bf16x8*>(p + 32);
  f.a2 = *reinterpret_cast<const bf16x8*>(p + 64);
  return f;
}

// ---- one 16x96 layer, weights as global B-frags (L1/L2-resident) ------------
__device__ __forceinline__ void layer_g(Frags f, const u16* __restrict__ wb,
    const float* __restrict__ bias, u16* dst, int dstStride, size_t rowBase,
    bool relu, int lane)
{
  int t16 = lane & 15, q = lane >> 4;
  #pragma unroll
  for (int nt = 0; nt < 6; nt++){
    float b = bias ? bias[nt * 16 + t16] : 0.f;
    f32x4 acc = {b, b, b, b};
    const u16* wp = wb + nt * 1536 + lane * 8;
    acc = MFMA(f.a0, *reinterpret_cast<const bf16x8*>(wp),        acc);
    acc = MFMA(f.a1, *reinterpret_cast<const bf16x8*>(wp + 512),  acc);
    acc = MFMA(f.a2, *reinterpret_cast<const bf16x8*>(wp + 1024), acc);
    #pragma unroll
    for (int j = 0; j < 4; j++){
      float v = acc[j];
      if (relu) v = fmaxf(v, 0.f);
      dst[(rowBase + q * 4 + j) * (size_t)dstStride + nt * 16 + t16] = f2bf(v);
    }
  }
}

// 3 col-tiles (jt0..jt0+2) accumulated into acc[tbase..tbase+3)
__device__ __forceinline__ void mfma3_g(f32x4* acc, int tbase, Frags f,
    const u16* __restrict__ wb, int jt0, int lane)
{
  #pragma unroll
  for (int jt = 0; jt < 3; jt++){
    const u16* wp = wb + (jt0 + jt) * 1536 + lane * 8;
    acc[tbase + jt] = MFMA(f.a0, *reinterpret_cast<const bf16x8*>(wp),        acc[tbase + jt]);
    acc[tbase + jt] = MFMA(f.a1, *reinterpret_cast<const bf16x8*>(wp + 512),  acc[tbase + jt]);
    acc[tbase + jt] = MFMA(f.a2, *reinterpret_cast<const bf16x8*>(wp + 1024), acc[tbase + jt]);
  }
}

// ============================================================================
// K_prep2: f32 weights -> bf16 B-fragment layout.
// frag elem (f, l, j): nt=f/3, kc=f%3, n=nt*16+(l&15), k=(l>>4)*8+kc*32+j
__global__ __launch_bounds__(256) void k_prep2(const float* __restrict__ crW,
    const float* __restrict__ drW, const float* __restrict__ gmW1,
    const float* __restrict__ gmW2, const float* __restrict__ rW12,
    const float* __restrict__ Wih, const float* __restrict__ Whh,
    u16* __restrict__ pWB)
{
  int b = blockIdx.x, tid = threadIdx.x;
  u16* dst = pWB + b * FCH;
  if (b < 12){
    const float* src;                           // row-major [k][n]
    if (b < 3)       src = crW  + b * 9216;
    else if (b < 6)  src = drW  + (b - 3) * 9216;
    else if (b == 6) src = gmW1 + 9216;
    else if (b == 7) src = gmW1 + 18432;
    else if (b < 10) src = gmW2 + (b - 8) * 9216;
    else             src = rW12 + (b - 10) * 9216;
    #pragma unroll
    for (int i = 0; i < 36; i++){
      int idx = tid + i * 256;
      int f = idx >> 9, rem = idx & 511, l = rem >> 3, j = rem & 7;
      int nt = f / 3, kc = f - nt * 3;
      int n = nt * 16 + (l & 15);
      int k = ((l >> 4) << 3) + kc * 32 + j;
      dst[idx] = f2bf(src[k * 96 + n]);
    }
  } else {
    int bb = b - 12;                            // 0..3 Wih chunks, 4..7 Whh
    const float* src = (bb < 4 ? Wih : Whh) + (bb & 3) * 9216;  // [n][k]
    #pragma unroll
    for (int i = 0; i < 36; i++){
      int idx = tid + i * 256;
      int f = idx >> 9, rem = idx & 511, l = rem >> 3, j = rem & 7;
      int nt = f / 3, kc = f - nt * 3;
      int n = nt * 16 + (l & 15);
      int k = ((l >> 4) << 3) + kc * 32 + j;
      dst[idx] = f2bf(src[n * 96 + k]);
    }
  }
}

// K0: tables (f32)
__global__ void k_tables(const float* __restrict__ eW1, const float* __restrict__ eb1,
                         const float* __restrict__ eW2, const float* __restrict__ eb2,
                         const float* __restrict__ gmW1, const float* __restrict__ gmb1,
                         float* __restrict__ XTab, float* __restrict__ XgTab)
{
  __shared__ float sX[3][96];
  int j = threadIdx.x;
  if (j < 96){
    for (int ch = 0; ch < 3; ch++){
      float acc = eb2[j];
      for (int e = 0; e < 16; e++){
        float hv = fmaxf(eW1[ch * 16 + e] + eb1[e], 0.f);
        acc += hv * eW2[e * 96 + j];
      }
      sX[ch][j] = acc;
      XTab[ch * 96 + j] = acc;
    }
  }
  __syncthreads();
  if (j < 96){
    for (int ch = 0; ch < 3; ch++){
      float acc = gmb1[j];
      for (int k = 0; k < 96; k++) acc += sX[ch][k] * gmW1[k * 96 + j];
      XgTab[ch * 96 + j] = acc;
    }
  }
}

// K_init: h only (c0 read directly on iter 0)
__global__ __launch_bounds__(256) void k_init(const int* __restrict__ inputs,
    const float* __restrict__ XTab, u16* __restrict__ h)
{
  int idx = blockIdx.x * 256 + threadIdx.x;     // exactly MROWS*12
  int m = idx / 12, h8 = idx - m * 12;
  int bn = m / 9, d = m - bn * 9;
  int inp = inputs[bn];
  int ch = (inp == 0) ? 0 : ((inp == d + 1) ? 1 : 2);
  const float* xt = XTab + ch * 96 + h8 * 8;
  u16* hp = h + (size_t)m * 96 + h8 * 8;
  #pragma unroll
  for (int e = 0; e < 8; e++) hp[e] = f2bf(xt[e]);
}

// K_AB3: h -> cr3 -> @W1b = Y;  h -> dr3 -> @W1c = Z. Barrier-free.
__global__ __launch_bounds__(256) void k_ab3(const u16* __restrict__ h,
    u16* __restrict__ Y, u16* __restrict__ Z,
    const u16* __restrict__ pWB, const float* __restrict__ crB,
    const float* __restrict__ drB)
{
  __shared__ u16 sA[64 * LDP];                  // wave-private 16-row slices
  const int tid = threadIdx.x, lane = tid & 63, wave = tid >> 6;
  const int wrow = wave * 16;
  const size_t rbase = (size_t)blockIdx.x * 64;

  Frags hf = load_afrags_g(h, rbase + wrow, lane);

  layer_g(hf, pWB, crB, sA, LDP, wrow, true, lane);                  lds_fence();
  Frags f = load_afrags_s(sA, wrow, lane);
  layer_g(f, pWB + 1 * FCH, crB + 96, sA, LDP, wrow, true, lane);    lds_fence();
  f = load_afrags_s(sA, wrow, lane);
  layer_g(f, pWB + 2 * FCH, crB + 192, sA, LDP, wrow, false, lane);  lds_fence();
  f = load_afrags_s(sA, wrow, lane);
  layer_g(f, pWB + 6 * FCH, nullptr, Y, 96, rbase + wrow, false, lane);
  lds_fence();

  layer_g(hf, pWB + 3 * FCH, drB, sA, LDP, wrow, true, lane);        lds_fence();
  f = load_afrags_s(sA, wrow, lane);
  layer_g(f, pWB + 4 * FCH, drB + 96, sA, LDP, wrow, true, lane);    lds_fence();
  f = load_afrags_s(sA, wrow, lane);
  layer_g(f, pWB + 5 * FCH, drB + 192, sA, LDP, wrow, false, lane);  lds_fence();
  f = load_afrags_s(sA, wrow, lane);
  layer_g(f, pWB + 7 * FCH, nullptr, Z, 96, rbase + wrow, false, lane);
}

// K_scell: Ssum[bn,:] = sum_d Y[bn,d,:]
__global__ __launch_bounds__(256) void k_scell(const u16* __restrict__ Y,
    u16* __restrict__ Ssum)
{
  int idx = blockIdx.x * 256 + threadIdx.x;     // exactly BN*12
  int bn = idx / 12, h8 = idx - bn * 12;
  const u16* base = Y + (size_t)bn * 864 + h8 * 8;
  float s[8];
  #pragma unroll
  for (int e = 0; e < 8; e++) s[e] = 0.f;
  #pragma unroll
  for (int d = 0; d < 9; d++){
    u16x8 v = *reinterpret_cast<const u16x8*>(base + d * 96);
    #pragma unroll
    for (int e = 0; e < 8; e++) s[e] += bf2f(v[e]);
  }
  u16x8 o;
  #pragma unroll
  for (int e = 0; e < 8; e++) o[e] = f2bf(s[e]);
  *reinterpret_cast<u16x8*>(Ssum + (size_t)bn * 96 + h8 * 8) = o;
}

__device__ __forceinline__ void addrow(float* s, const u16* p){
  u16x8 t = *reinterpret_cast<const u16x8*>(p);
  #pragma unroll
  for (int e = 0; e < 8; e++) s[e] += bf2f(t[e]);
}

// K4: msg_digit in-place per (b,d) slice
__global__ __launch_bounds__(256) void k_msgdigit(u16* __restrict__ buf)
{
  __shared__ u16 sT[81 * LDP];
  const int tid = threadIdx.x;
  const int b = blockIdx.x / 9, d = blockIdx.x - b * 9;
  const size_t base = ((size_t)b * 729 + d) * 96;
  for (int i = tid; i < 972; i += 256){
    int n = i / 12, k8 = i - n * 12;
    *reinterpret_cast<u16x8*>(sT + n * LDP + k8 * 8) =
      *reinterpret_cast<const u16x8*>(buf + base + (size_t)n * 864 + k8 * 8);
  }
  __syncthreads();
  for (int i = tid; i < 972; i += 256){
    int m = i / 12, k8 = i - m * 12;
    int r = m / 9, cc = m - r * 9;
    int br = (r / 3) * 3, bc = (cc / 3) * 3;
    float s[8];
    #pragma unroll
    for (int e = 0; e < 8; e++) s[e] = 0.f;
    #pragma unroll
    for (int c2 = 0; c2 < 9; c2++) if (c2 != cc) addrow(s, sT + (r * 9 + c2) * LDP + k8 * 8);
    #pragma unroll
    for (int r2 = 0; r2 < 9; r2++) if (r2 != r) addrow(s, sT + (r2 * 9 + cc) * LDP + k8 * 8);
    #pragma unroll
    for (int r2 = 0; r2 < 3; r2++)
      #pragma unroll
      for (int c2 = 0; c2 < 3; c2++){
        int rr = br + r2, c3 = bc + c2;
        if (rr != r && c3 != cc) addrow(s, sT + (rr * 9 + c3) * LDP + k8 * 8);
      }
    u16x8 o;
    #pragma unroll
    for (int e = 0; e < 8; e++) o[e] = f2bf(s[e]);
    *reinterpret_cast<u16x8*>(buf + base + (size_t)m * 864 + k8 * 8) = o;
  }
}

// K_GLR5: g1 + gm W2 + LSTM split by OUTPUT COLUMNS (two halves, acc[12] each)
// + readout. Barrier-free. Per-element math bit-identical to glr3.
__global__ __launch_bounds__(256, 3) void k_glr5(const u16* __restrict__ Y,
    const u16* __restrict__ Zd, const u16* __restrict__ Ssum,
    const int* __restrict__ inputs, const float* __restrict__ XgTab,
    const u16* __restrict__ pWB, const float* __restrict__ gmb2,
    u16* __restrict__ h, const float* __restrict__ cin, float* __restrict__ cout,
    const float* __restrict__ bih, const float* __restrict__ bhh,
    const float* __restrict__ rb12, const float* __restrict__ rW3,
    const float* __restrict__ rb3, float* __restrict__ out)
{
  __shared__ u16 sA[64 * LDP];                  // wave-private 16-row slices
  const int tid = threadIdx.x, lane = tid & 63, wave = tid >> 6;
  const int t16 = lane & 15, q = lane >> 4;
  const int wrow = wave * 16;
  const size_t rbase = (size_t)blockIdx.x * 64;

  Frags ah = load_afrags_g(h, rbase + wrow, lane);

  // g1 = relu(Xg[ch] + (Ssum - Y) + Zd) -> own sA rows
  for (int i = lane; i < 192; i += 64){
    int rl = i / 12, kc = i - rl * 12;
    int m = (int)rbase + wrow + rl;
    int bn = m / 9, d = m - bn * 9;
    int inp = inputs[bn];
    int ch = (inp == 0) ? 0 : ((inp == d + 1) ? 1 : 2);
    const float* xg = XgTab + ch * 96 + kc * 8;
    u16x8 vy = *reinterpret_cast<const u16x8*>(Y    + (size_t)m * 96 + kc * 8);
    u16x8 vz = *reinterpret_cast<const u16x8*>(Zd   + (size_t)m * 96 + kc * 8);
    u16x8 vs = *reinterpret_cast<const u16x8*>(Ssum + (size_t)bn * 96 + kc * 8);
    u16x8 o;
    #pragma unroll
    for (int e = 0; e < 8; e++)
      o[e] = f2bf(fmaxf(xg[e] + bf2f(vs[e]) - bf2f(vy[e]) + bf2f(vz[e]), 0.f));
    *reinterpret_cast<u16x8*>(sA + (wrow + rl) * LDP + kc * 8) = o;
  }
  lds_fence();

  Frags f = load_afrags_s(sA, wrow, lane);
  layer_g(f, pWB + 8 * FCH, gmb2, sA, LDP, wrow, true, lane);        lds_fence();
  f = load_afrags_s(sA, wrow, lane);
  layer_g(f, pWB + 9 * FCH, gmb2 + 96, sA, LDP, wrow, false, lane);  lds_fence();
  Frags ax = load_afrags_s(sA, wrow, lane);

  // ---- LSTM: two column-halves; acc[g*3+jt] for cols (jt0+jt)*16 ----
  #pragma unroll
  for (int half = 0; half < 2; half++){
    const int jt0 = half * 3;
    f32x4 acc[12];
    #pragma unroll
    for (int g = 0; g < 4; g++)
      #pragma unroll
      for (int jt = 0; jt < 3; jt++){
        int n = g * 96 + (jt0 + jt) * 16 + t16;
        float b = bih[n] + bhh[n];
        f32x4 a = {b, b, b, b};
        acc[g * 3 + jt] = a;
      }
    #pragma unroll
    for (int g = 0; g < 4; g++)
      mfma3_g(acc, g * 3, ax, pWB + (12 + g) * FCH, jt0, lane);
    #pragma unroll
    for (int g = 0; g < 4; g++)
      mfma3_g(acc, g * 3, ah, pWB + (16 + g) * FCH, jt0, lane);

    // epilogue for these 48 cols
    #pragma unroll
    for (int jt = 0; jt < 3; jt++)
      #pragma unroll
      for (int j = 0; j < 4; j++){
        size_t m = rbase + wrow + q * 4 + j;
        int col = (jt0 + jt) * 16 + t16;
        float iv = acc[0 * 3 + jt][j];
        float fv = acc[1 * 3 + jt][j];
        float gv = acc[2 * 3 + jt][j];
        float ov = acc[3 * 3 + jt][j];
        float cold = cin[m * 96 + col];
        float cn = sigf(fv) * cold + sigf(iv) * tanhf_(gv);
        float hn = sigf(ov) * tanhf_(cn);
        cout[m * 96 + col] = cn;
        u16 hb = f2bf(hn);
        h[m * 96 + col] = hb;
        sA[(wrow + q * 4 + j) * LDP + col] = hb;
      }
  }
  lds_fence();

  // Readout
  f = load_afrags_s(sA, wrow, lane);
  layer_g(f, pWB + 10 * FCH, rb12, sA, LDP, wrow, true, lane);       lds_fence();
  f = load_afrags_s(sA, wrow, lane);
  layer_g(f, pWB + 11 * FCH, rb12 + 96, sA, LDP, wrow, true, lane);  lds_fence();

  // Final dot over own rows: out[row] = sA[row,:] . rW3 + rb3
  int row = tid >> 2, part = tid & 3;
  float s = 0.f;
  const u16* rp = sA + row * LDP + part * 24;
  #pragma unroll
  for (int k = 0; k < 24; k++) s += bf2f(rp[k]) * rW3[part * 24 + k];
  s += __shfl_xor(s, 1);
  s += __shfl_xor(s, 2);
  if (part == 0) out[rbase + row] = s + rb3[0];
}

// ============================================================================
extern "C" void kernel_launch(void* const* d_in, const int* in_sizes, int n_in,
                              void* d_out, int out_size, void* d_ws, size_t ws_size,
                              hipStream_t stream)
{
  (void)in_sizes; (void)n_in; (void)out_size; (void)ws_size;
  const int*   inputs = (const int*)d_in[0];
  const float* c0     = (const float*)d_in[1];
  const float* eW1  = (const float*)d_in[4];
  const float* eb1  = (const float*)d_in[5];
  const float* eW2  = (const float*)d_in[6];
  const float* eb2  = (const float*)d_in[7];
  const float* crW  = (const float*)d_in[8];
  const float* crB  = (const float*)d_in[9];
  const float* drW  = (const float*)d_in[10];
  const float* drB  = (const float*)d_in[11];
  const float* gmW1 = (const float*)d_in[12];
  const float* gmb1 = (const float*)d_in[13];
  const float* gmW2 = (const float*)d_in[14];
  const float* gmb2 = (const float*)d_in[15];
  const float* Wih  = (const float*)d_in[16];
  const float* Whh  = (const float*)d_in[17];
  const float* bih  = (const float*)d_in[18];
  const float* bhh  = (const float*)d_in[19];
  const float* rW12 = (const float*)d_in[20];
  const float* rb12 = (const float*)d_in[21];
  const float* rW3  = (const float*)d_in[22];
  const float* rb3  = (const float*)d_in[23];

  char* ws = (char*)d_ws;
  float* XgTab = (float*)(ws);
  float* XTab  = (float*)(ws + 4096);
  u16*   pWB   = (u16*)(ws + 8192);              // 20*9216*2 = 368640 B
  u16* h  = (u16*)(ws + 8192 + 401408);
  u16* B1 = h  + (size_t)MROWS * 96;             // Y
  u16* B2 = B1 + (size_t)MROWS * 96;             // Z / Zd
  float* c = (float*)(B2 + (size_t)MROWS * 96);
  u16* Ssum = (u16*)(c + (size_t)MROWS * 96);    // BN*96 bf16
  float* out = (float*)d_out;

  k_prep2<<<20, 256, 0, stream>>>(crW, drW, gmW1, gmW2, rW12, Wih, Whh, pWB);
  k_tables<<<1, 128, 0, stream>>>(eW1, eb1, eW2, eb2, gmW1, gmb1, XTab, XgTab);
  k_init<<<(MROWS * 12) / 256, 256, 0, stream>>>(inputs, XTab, h);

  for (int it = 0; it < 4; ++it){
    const float* cin = (it == 0) ? c0 : c;
    k_ab3<<<GRID_TILE, 256, 0, stream>>>(h, B1, B2, pWB, crB, drB);
    k_scell<<<(BN * 12) / 256, 256, 0, stream>>>(B1, Ssum);
    k_msgdigit<<<128 * 9, 256, 0, stream>>>(B2);
    k_glr5<<<GRID_TILE, 256, 0, stream>>>(B1, B2, Ssum, inputs, XgTab, pWB, gmb2,
                                          h, cin, c, bih, bhh, rb12, rW3, rb3,
                                          out + (size_t)it * MROWS);
  }
}

// Round 10
// 777.601 us; speedup vs baseline: 1.1536x; 1.1423x over previous
//
#include <hip/hip_runtime.h>
#include <hip/hip_bf16.h>

typedef unsigned short u16;
typedef __bf16 bf16x8 __attribute__((ext_vector_type(8)));   // MFMA A/B operand (4 VGPRs)
typedef float  f32x4  __attribute__((ext_vector_type(4)));   // MFMA C/D operand
typedef u16    u16x8  __attribute__((ext_vector_type(8)));

#define HID   96
#define LDP   104          // padded LDS row stride for activation slices
#define MROWS 93312        // B*N*D
#define BN    10368        // B*N
#define GRID_TILE 1458     // MROWS/64

// B-fragment-ordered weights: 20 chunks x 18 frags x 512 elems (1KB frags)
// chunk: 0-2 crW, 3-5 drW, 6 W1b, 7 W1c, 8-9 gmW2, 10-11 rW12,
//        12-15 Wih (gate n-ranges i,f,g,o), 16-19 Whh
#define FCH 9216           // elems per chunk (18*512)

#define MFMA(a,b,c) __builtin_amdgcn_mfma_f32_16x16x32_bf16((a),(b),(c),0,0,0)

__device__ __forceinline__ float bf2f(u16 x){
  union { float f; unsigned u; } v; v.u = ((unsigned)x) << 16; return v.f;
}
__device__ __forceinline__ u16 f2bf(float f){
  union { float f; unsigned u; } v; v.f = f;
  unsigned r = v.u + 0x7fffu + ((v.u >> 16) & 1u);   // RNE
  return (u16)(r >> 16);
}
__device__ __forceinline__ float sigf(float x){ return 1.f/(1.f + __expf(-x)); }
__device__ __forceinline__ float tanhf_(float x){
  float xx = fminf(fmaxf(x, -15.f), 15.f);
  float e = __expf(-2.f * xx);
  return (1.f - e) / (1.f + e);
}
// in-wave LDS write->read ordering (no cross-wave data: barrier-free kernels)
__device__ __forceinline__ void lds_fence(){
  asm volatile("s_waitcnt lgkmcnt(0)" ::: "memory");
}

// ---- fragment loaders -------------------------------------------------------
struct Frags { bf16x8 a0, a1, a2; };

__device__ __forceinline__ Frags load_afrags_g(const u16* __restrict__ A, size_t row0, int lane){
  int t16 = lane & 15, q = lane >> 4;
  const u16* p = A + (row0 + (size_t)t16) * 96 + q * 8;
  Frags f;
  f.a0 = *reinterpret_cast<const bf16x8*>(p);
  f.a1 = *reinterpret_cast<const bf16x8*>(p + 32);
  f.a2 = *reinterpret_cast<const bf16x8*>(p + 64);
  return f;
}
__device__ __forceinline__ Frags load_afrags_s(const u16* sA, int row0, int lane){
  int t16 = lane & 15, q = lane >> 4;
  const u16* p = sA + (row0 + t16) * LDP + q * 8;
  Frags f;
  f.a0 = *reinterpret_cast<const bf16x8*>(p);
  f.a1 = *reinterpret_cast<const bf16x8*>(p + 32);
  f.a2 = *reinterpret_cast<const bf16x8*>(p + 64);
  return f;
}

// ---- one 16x96 layer, weights as global B-frags (L1/L2-resident) ------------
__device__ __forceinline__ void layer_g(Frags f, const u16* __restrict__ wb,
    const float* __restrict__ bias, u16* dst, int dstStride, size_t rowBase,
    bool relu, int lane)
{
  int t16 = lane & 15, q = lane >> 4;
  #pragma unroll
  for (int nt = 0; nt < 6; nt++){
    float b = bias ? bias[nt * 16 + t16] : 0.f;
    f32x4 acc = {b, b, b, b};
    const u16* wp = wb + nt * 1536 + lane * 8;
    acc = MFMA(f.a0, *reinterpret_cast<const bf16x8*>(wp),        acc);
    acc = MFMA(f.a1, *reinterpret_cast<const bf16x8*>(wp + 512),  acc);
    acc = MFMA(f.a2, *reinterpret_cast<const bf16x8*>(wp + 1024), acc);
    #pragma unroll
    for (int j = 0; j < 4; j++){
      float v = acc[j];
      if (relu) v = fmaxf(v, 0.f);
      dst[(rowBase + q * 4 + j) * (size_t)dstStride + nt * 16 + t16] = f2bf(v);
    }
  }
}

// 6 col-tiles accumulated into acc[tbase..tbase+6), weights from global frags
__device__ __forceinline__ void mfma6_g(f32x4* acc, int tbase, Frags f,
    const u16* __restrict__ wb, int lane)
{
  #pragma unroll
  for (int jt = 0; jt < 6; jt++){
    const u16* wp = wb + jt * 1536 + lane * 8;
    acc[tbase + jt] = MFMA(f.a0, *reinterpret_cast<const bf16x8*>(wp),        acc[tbase + jt]);
    acc[tbase + jt] = MFMA(f.a1, *reinterpret_cast<const bf16x8*>(wp + 512),  acc[tbase + jt]);
    acc[tbase + jt] = MFMA(f.a2, *reinterpret_cast<const bf16x8*>(wp + 1024), acc[tbase + jt]);
  }
}

// ============================================================================
// K_prep2: f32 weights -> bf16 B-fragment layout.
// frag elem (f, l, j): nt=f/3, kc=f%3, n=nt*16+(l&15), k=(l>>4)*8+kc*32+j
__global__ __launch_bounds__(256) void k_prep2(const float* __restrict__ crW,
    const float* __restrict__ drW, const float* __restrict__ gmW1,
    const float* __restrict__ gmW2, const float* __restrict__ rW12,
    const float* __restrict__ Wih, const float* __restrict__ Whh,
    u16* __restrict__ pWB)
{
  int b = blockIdx.x, tid = threadIdx.x;
  u16* dst = pWB + b * FCH;
  if (b < 12){
    const float* src;                           // row-major [k][n]
    if (b < 3)       src = crW  + b * 9216;
    else if (b < 6)  src = drW  + (b - 3) * 9216;
    else if (b == 6) src = gmW1 + 9216;
    else if (b == 7) src = gmW1 + 18432;
    else if (b < 10) src = gmW2 + (b - 8) * 9216;
    else             src = rW12 + (b - 10) * 9216;
    #pragma unroll
    for (int i = 0; i < 36; i++){
      int idx = tid + i * 256;
      int f = idx >> 9, rem = idx & 511, l = rem >> 3, j = rem & 7;
      int nt = f / 3, kc = f - nt * 3;
      int n = nt * 16 + (l & 15);
      int k = ((l >> 4) << 3) + kc * 32 + j;
      dst[idx] = f2bf(src[k * 96 + n]);
    }
  } else {
    int bb = b - 12;                            // 0..3 Wih chunks, 4..7 Whh
    const float* src = (bb < 4 ? Wih : Whh) + (bb & 3) * 9216;  // [n][k]
    #pragma unroll
    for (int i = 0; i < 36; i++){
      int idx = tid + i * 256;
      int f = idx >> 9, rem = idx & 511, l = rem >> 3, j = rem & 7;
      int nt = f / 3, kc = f - nt * 3;
      int n = nt * 16 + (l & 15);
      int k = ((l >> 4) << 3) + kc * 32 + j;
      dst[idx] = f2bf(src[n * 96 + k]);
    }
  }
}

// K0: tables (f32)
__global__ void k_tables(const float* __restrict__ eW1, const float* __restrict__ eb1,
                         const float* __restrict__ eW2, const float* __restrict__ eb2,
                         const float* __restrict__ gmW1, const float* __restrict__ gmb1,
                         float* __restrict__ XTab, float* __restrict__ XgTab)
{
  __shared__ float sX[3][96];
  int j = threadIdx.x;
  if (j < 96){
    for (int ch = 0; ch < 3; ch++){
      float acc = eb2[j];
      for (int e = 0; e < 16; e++){
        float hv = fmaxf(eW1[ch * 16 + e] + eb1[e], 0.f);
        acc += hv * eW2[e * 96 + j];
      }
      sX[ch][j] = acc;
      XTab[ch * 96 + j] = acc;
    }
  }
  __syncthreads();
  if (j < 96){
    for (int ch = 0; ch < 3; ch++){
      float acc = gmb1[j];
      for (int k = 0; k < 96; k++) acc += sX[ch][k] * gmW1[k * 96 + j];
      XgTab[ch * 96 + j] = acc;
    }
  }
}

// K_init: h only (c0 read directly on iter 0)
__global__ __launch_bounds__(256) void k_init(const int* __restrict__ inputs,
    const float* __restrict__ XTab, u16* __restrict__ h)
{
  int idx = blockIdx.x * 256 + threadIdx.x;     // exactly MROWS*12
  int m = idx / 12, h8 = idx - m * 12;
  int bn = m / 9, d = m - bn * 9;
  int inp = inputs[bn];
  int ch = (inp == 0) ? 0 : ((inp == d + 1) ? 1 : 2);
  const float* xt = XTab + ch * 96 + h8 * 8;
  u16* hp = h + (size_t)m * 96 + h8 * 8;
  #pragma unroll
  for (int e = 0; e < 8; e++) hp[e] = f2bf(xt[e]);
}

// K_AB3: h -> cr3 -> @W1b = Y;  h -> dr3 -> @W1c = Z. Barrier-free.
__global__ __launch_bounds__(256) void k_ab3(const u16* __restrict__ h,
    u16* __restrict__ Y, u16* __restrict__ Z,
    const u16* __restrict__ pWB, const float* __restrict__ crB,
    const float* __restrict__ drB)
{
  __shared__ u16 sA[64 * LDP];                  // wave-private 16-row slices
  const int tid = threadIdx.x, lane = tid & 63, wave = tid >> 6;
  const int wrow = wave * 16;
  const size_t rbase = (size_t)blockIdx.x * 64;

  Frags hf = load_afrags_g(h, rbase + wrow, lane);

  layer_g(hf, pWB, crB, sA, LDP, wrow, true, lane);                  lds_fence();
  Frags f = load_afrags_s(sA, wrow, lane);
  layer_g(f, pWB + 1 * FCH, crB + 96, sA, LDP, wrow, true, lane);    lds_fence();
  f = load_afrags_s(sA, wrow, lane);
  layer_g(f, pWB + 2 * FCH, crB + 192, sA, LDP, wrow, false, lane);  lds_fence();
  f = load_afrags_s(sA, wrow, lane);
  layer_g(f, pWB + 6 * FCH, nullptr, Y, 96, rbase + wrow, false, lane);
  lds_fence();

  layer_g(hf, pWB + 3 * FCH, drB, sA, LDP, wrow, true, lane);        lds_fence();
  f = load_afrags_s(sA, wrow, lane);
  layer_g(f, pWB + 4 * FCH, drB + 96, sA, LDP, wrow, true, lane);    lds_fence();
  f = load_afrags_s(sA, wrow, lane);
  layer_g(f, pWB + 5 * FCH, drB + 192, sA, LDP, wrow, false, lane);  lds_fence();
  f = load_afrags_s(sA, wrow, lane);
  layer_g(f, pWB + 7 * FCH, nullptr, Z, 96, rbase + wrow, false, lane);
}

__device__ __forceinline__ void addrow(float* s, const u16* p){
  u16x8 t = *reinterpret_cast<const u16x8*>(p);
  #pragma unroll
  for (int e = 0; e < 8; e++) s[e] += bf2f(t[e]);
}

// K_MSG: fused k_msgdigit (blocks 0..1151, Z in-place) + k_scell (blocks
// 1152..1637, Y -> Ssum). Independent buffers.
__global__ __launch_bounds__(256) void k_msg(u16* __restrict__ Z,
    const u16* __restrict__ Y, u16* __restrict__ Ssum)
{
  __shared__ u16 sT[81 * LDP];
  const int tid = threadIdx.x;
  if (blockIdx.x >= 1152){
    // ---- scell part: Ssum[bn,:] = sum_d Y[bn,d,:] ----
    int idx = (blockIdx.x - 1152) * 256 + tid;  // exactly BN*12
    int bn = idx / 12, h8 = idx - bn * 12;
    const u16* base = Y + (size_t)bn * 864 + h8 * 8;
    float s[8];
    #pragma unroll
    for (int e = 0; e < 8; e++) s[e] = 0.f;
    #pragma unroll
    for (int d = 0; d < 9; d++){
      u16x8 v = *reinterpret_cast<const u16x8*>(base + d * 96);
      #pragma unroll
      for (int e = 0; e < 8; e++) s[e] += bf2f(v[e]);
    }
    u16x8 o;
    #pragma unroll
    for (int e = 0; e < 8; e++) o[e] = f2bf(s[e]);
    *reinterpret_cast<u16x8*>(Ssum + (size_t)bn * 96 + h8 * 8) = o;
    return;
  }
  // ---- msgdigit part: per (b,d) slice of Z, 20 Sudoku neighbors ----
  const int b = blockIdx.x / 9, d = blockIdx.x - b * 9;
  const size_t base = ((size_t)b * 729 + d) * 96;
  for (int i = tid; i < 972; i += 256){
    int n = i / 12, k8 = i - n * 12;
    *reinterpret_cast<u16x8*>(sT + n * LDP + k8 * 8) =
      *reinterpret_cast<const u16x8*>(Z + base + (size_t)n * 864 + k8 * 8);
  }
  __syncthreads();
  for (int i = tid; i < 972; i += 256){
    int m = i / 12, k8 = i - m * 12;
    int r = m / 9, cc = m - r * 9;
    int br = (r / 3) * 3, bc = (cc / 3) * 3;
    float s[8];
    #pragma unroll
    for (int e = 0; e < 8; e++) s[e] = 0.f;
    #pragma unroll
    for (int c2 = 0; c2 < 9; c2++) if (c2 != cc) addrow(s, sT + (r * 9 + c2) * LDP + k8 * 8);
    #pragma unroll
    for (int r2 = 0; r2 < 9; r2++) if (r2 != r) addrow(s, sT + (r2 * 9 + cc) * LDP + k8 * 8);
    #pragma unroll
    for (int r2 = 0; r2 < 3; r2++)
      #pragma unroll
      for (int c2 = 0; c2 < 3; c2++){
        int rr = br + r2, c3 = bc + c2;
        if (rr != r && c3 != cc) addrow(s, sT + (rr * 9 + c3) * LDP + k8 * 8);
      }
    u16x8 o;
    #pragma unroll
    for (int e = 0; e < 8; e++) o[e] = f2bf(s[e]);
    *reinterpret_cast<u16x8*>(Z + base + (size_t)m * 864 + k8 * 8) = o;
  }
}

// K_GLR6: glr3 structure (single acc[24] pass, full-width epilogue) with the
// 24 cin loads PREFETCHED at kernel entry (HBM reads in flight under MFMAs).
__global__ __launch_bounds__(256) void k_glr6(const u16* __restrict__ Y,
    const u16* __restrict__ Zd, const u16* __restrict__ Ssum,
    const int* __restrict__ inputs, const float* __restrict__ XgTab,
    const u16* __restrict__ pWB, const float* __restrict__ gmb2,
    u16* __restrict__ h, const float* __restrict__ cin, float* __restrict__ cout,
    const float* __restrict__ bih, const float* __restrict__ bhh,
    const float* __restrict__ rb12, const float* __restrict__ rW3,
    const float* __restrict__ rb3, float* __restrict__ out)
{
  __shared__ u16 sA[64 * LDP];                  // wave-private 16-row slices
  const int tid = threadIdx.x, lane = tid & 63, wave = tid >> 6;
  const int t16 = lane & 15, q = lane >> 4;
  const int wrow = wave * 16;
  const size_t rbase = (size_t)blockIdx.x * 64;

  // ---- EARLY: issue all HBM reads this wave will ever need ----
  float cold[6][4];                              // c-state prefetch (epilogue use)
  #pragma unroll
  for (int jt = 0; jt < 6; jt++)
    #pragma unroll
    for (int j = 0; j < 4; j++)
      cold[jt][j] = cin[(rbase + wrow + q * 4 + j) * 96 + jt * 16 + t16];
  Frags ah = load_afrags_g(h, rbase + wrow, lane);

  // g1 = relu(Xg[ch] + (Ssum - Y) + Zd) -> own sA rows
  for (int i = lane; i < 192; i += 64){
    int rl = i / 12, kc = i - rl * 12;
    int m = (int)rbase + wrow + rl;
    int bn = m / 9, d = m - bn * 9;
    int inp = inputs[bn];
    int ch = (inp == 0) ? 0 : ((inp == d + 1) ? 1 : 2);
    const float* xg = XgTab + ch * 96 + kc * 8;
    u16x8 vy = *reinterpret_cast<const u16x8*>(Y    + (size_t)m * 96 + kc * 8);
    u16x8 vz = *reinterpret_cast<const u16x8*>(Zd   + (size_t)m * 96 + kc * 8);
    u16x8 vs = *reinterpret_cast<const u16x8*>(Ssum + (size_t)bn * 96 + kc * 8);
    u16x8 o;
    #pragma unroll
    for (int e = 0; e < 8; e++)
      o[e] = f2bf(fmaxf(xg[e] + bf2f(vs[e]) - bf2f(vy[e]) + bf2f(vz[e]), 0.f));
    *reinterpret_cast<u16x8*>(sA + (wrow + rl) * LDP + kc * 8) = o;
  }
  lds_fence();

  Frags f = load_afrags_s(sA, wrow, lane);
  layer_g(f, pWB + 8 * FCH, gmb2, sA, LDP, wrow, true, lane);        lds_fence();
  f = load_afrags_s(sA, wrow, lane);
  layer_g(f, pWB + 9 * FCH, gmb2 + 96, sA, LDP, wrow, false, lane);  lds_fence();
  Frags ax = load_afrags_s(sA, wrow, lane);

  // LSTM gates: 24 col-tiles (n = 0..383)
  f32x4 acc[24];
  #pragma unroll
  for (int t = 0; t < 24; t++){
    int n = t * 16 + t16;
    float b = bih[n] + bhh[n];
    f32x4 a = {b, b, b, b};
    acc[t] = a;
  }
  #pragma unroll
  for (int c = 0; c < 4; c++) mfma6_g(acc, c * 6, ax, pWB + (12 + c) * FCH, lane);
  #pragma unroll
  for (int c = 0; c < 4; c++) mfma6_g(acc, c * 6, ah, pWB + (16 + c) * FCH, lane);

  // Epilogue: c/h update; h_new -> global + own sA rows (full 96-col width)
  #pragma unroll
  for (int jt = 0; jt < 6; jt++)
    #pragma unroll
    for (int j = 0; j < 4; j++){
      size_t m = rbase + wrow + q * 4 + j;
      int col = jt * 16 + t16;
      float iv = acc[0 * 6 + jt][j];
      float fv = acc[1 * 6 + jt][j];
      float gv = acc[2 * 6 + jt][j];
      float ov = acc[3 * 6 + jt][j];
      float cn = sigf(fv) * cold[jt][j] + sigf(iv) * tanhf_(gv);
      float hn = sigf(ov) * tanhf_(cn);
      cout[m * 96 + col] = cn;
      u16 hb = f2bf(hn);
      h[m * 96 + col] = hb;
      sA[(wrow + q * 4 + j) * LDP + col] = hb;
    }
  lds_fence();

  // Readout
  f = load_afrags_s(sA, wrow, lane);
  layer_g(f, pWB + 10 * FCH, rb12, sA, LDP, wrow, true, lane);       lds_fence();
  f = load_afrags_s(sA, wrow, lane);
  layer_g(f, pWB + 11 * FCH, rb12 + 96, sA, LDP, wrow, true, lane);  lds_fence();

  // Final dot over own rows: out[row] = sA[row,:] . rW3 + rb3
  int row = tid >> 2, part = tid & 3;
  float s = 0.f;
  const u16* rp = sA + row * LDP + part * 24;
  #pragma unroll
  for (int k = 0; k < 24; k++) s += bf2f(rp[k]) * rW3[part * 24 + k];
  s += __shfl_xor(s, 1);
  s += __shfl_xor(s, 2);
  if (part == 0) out[rbase + row] = s + rb3[0];
}

// ============================================================================
extern "C" void kernel_launch(void* const* d_in, const int* in_sizes, int n_in,
                              void* d_out, int out_size, void* d_ws, size_t ws_size,
                              hipStream_t stream)
{
  (void)in_sizes; (void)n_in; (void)out_size; (void)ws_size;
  const int*   inputs = (const int*)d_in[0];
  const float* c0     = (const float*)d_in[1];
  const float* eW1  = (const float*)d_in[4];
  const float* eb1  = (const float*)d_in[5];
  const float* eW2  = (const float*)d_in[6];
  const float* eb2  = (const float*)d_in[7];
  const float* crW  = (const float*)d_in[8];
  const float* crB  = (const float*)d_in[9];
  const float* drW  = (const float*)d_in[10];
  const float* drB  = (const float*)d_in[11];
  const float* gmW1 = (const float*)d_in[12];
  const float* gmb1 = (const float*)d_in[13];
  const float* gmW2 = (const float*)d_in[14];
  const float* gmb2 = (const float*)d_in[15];
  const float* Wih  = (const float*)d_in[16];
  const float* Whh  = (const float*)d_in[17];
  const float* bih  = (const float*)d_in[18];
  const float* bhh  = (const float*)d_in[19];
  const float* rW12 = (const float*)d_in[20];
  const float* rb12 = (const float*)d_in[21];
  const float* rW3  = (const float*)d_in[22];
  const float* rb3  = (const float*)d_in[23];

  char* ws = (char*)d_ws;
  float* XgTab = (float*)(ws);
  float* XTab  = (float*)(ws + 4096);
  u16*   pWB   = (u16*)(ws + 8192);              // 20*9216*2 = 368640 B
  u16* h  = (u16*)(ws + 8192 + 401408);
  u16* B1 = h  + (size_t)MROWS * 96;             // Y
  u16* B2 = B1 + (size_t)MROWS * 96;             // Z / Zd
  float* c = (float*)(B2 + (size_t)MROWS * 96);
  u16* Ssum = (u16*)(c + (size_t)MROWS * 96);    // BN*96 bf16
  float* out = (float*)d_out;

  k_prep2<<<20, 256, 0, stream>>>(crW, drW, gmW1, gmW2, rW12, Wih, Whh, pWB);
  k_tables<<<1, 128, 0, stream>>>(eW1, eb1, eW2, eb2, gmW1, gmb1, XTab, XgTab);
  k_init<<<(MROWS * 12) / 256, 256, 0, stream>>>(inputs, XTab, h);

  for (int it = 0; it < 4; ++it){
    const float* cin = (it == 0) ? c0 : c;
    k_ab3<<<GRID_TILE, 256, 0, stream>>>(h, B1, B2, pWB, crB, drB);
    k_msg<<<1152 + 486, 256, 0, stream>>>(B2, B1, Ssum);
    k_glr6<<<GRID_TILE, 256, 0, stream>>>(B1, B2, Ssum, inputs, XgTab, pWB, gmb2,
                                          h, cin, c, bih, bhh, rb12, rW3, rb3,
                                          out + (size_t)it * MROWS);
  }
}